// Round 7
// baseline (381.773 us; speedup 1.0000x reference)
//
#include <hip/hip_runtime.h>
#include <math.h>

#define D_MODEL 1024
#define NHEAD   16
#define DKH     64
#define DFF_    4096
#define BB      2
#define SS      2048
#define MTOT    (BB*SS)
#define EPSLN   1e-6f
#define NEG_SLOPE 0.01f

typedef unsigned short u16;
typedef unsigned int   u32;
typedef __bf16 bf16x8 __attribute__((ext_vector_type(8)));
typedef float  f32x4  __attribute__((ext_vector_type(4)));
typedef u16    u16x4  __attribute__((ext_vector_type(4)));

__device__ __forceinline__ u16 f2bf(float f) {
    u32 u = __float_as_uint(f);
    u = (u + 0x7fffu + ((u >> 16) & 1u)) >> 16;
    return (u16)u;
}
__device__ __forceinline__ float bf2f(u16 u) {
    return __uint_as_float(((u32)u) << 16);
}

__device__ __forceinline__ void gload_lds16(const u16* g, u16* l) {
    __builtin_amdgcn_global_load_lds(
        (const __attribute__((address_space(1))) u32*)g,
        (__attribute__((address_space(3))) u32*)l,
        16, 0, 0);
}

#define MF(a, b, c) __builtin_amdgcn_mfma_f32_16x16x32_bf16(a, b, c, 0, 0, 0)

// ---------------------------------------------------------------------------
// 64x64 fp32->bf16 transpose tile (device helper for prep kernel)
// ---------------------------------------------------------------------------
__device__ __forceinline__ void transpose_tile(const float* __restrict__ W,
        u16* __restrict__ WT, int N, int out_stride, int out_row_off,
        float scale, int bx, int by, u16* T)
{
    const int t  = threadIdx.x;
    const int n0 = bx * 64;
    const int k0 = by * 64;
    #pragma unroll
    for (int i = 0; i < 4; ++i) {
        int r = i * 16 + (t >> 4);          // k
        int c = (t & 15) * 4;               // n
        float4 v = *(const float4*)&W[(size_t)(k0 + r) * N + n0 + c];
        T[(c + 0) * 72 + r] = f2bf(v.x * scale);
        T[(c + 1) * 72 + r] = f2bf(v.y * scale);
        T[(c + 2) * 72 + r] = f2bf(v.z * scale);
        T[(c + 3) * 72 + r] = f2bf(v.w * scale);
    }
    __syncthreads();
    #pragma unroll
    for (int i = 0; i < 4; ++i) {
        int nr = i * 16 + (t >> 4);
        int kc = (t & 15) * 4;
        u16x4 o = { T[nr*72 + kc], T[nr*72 + kc + 1], T[nr*72 + kc + 2], T[nr*72 + kc + 3] };
        *(u16x4*)&WT[(size_t)(out_row_off + n0 + nr) * out_stride + k0 + kc] = o;
    }
}

// ---------------------------------------------------------------------------
// Fused prep: x f32->bf16 | 4 square W transposes | ff1 | ff2 | bias concat.
// ---------------------------------------------------------------------------
__global__ __launch_bounds__(256)
void prep(const float* __restrict__ x, u16* __restrict__ x_bf,
          const float* __restrict__ wq, const float* __restrict__ wk,
          const float* __restrict__ wv, const float* __restrict__ wo,
          const float* __restrict__ wff1, const float* __restrict__ wff2,
          u16* __restrict__ wqkvT, u16* __restrict__ woT,
          u16* __restrict__ wff1T, u16* __restrict__ wff2T,
          const float* __restrict__ bq, const float* __restrict__ bk,
          const float* __restrict__ bv, float* __restrict__ qkv_bias,
          float qscale)
{
    __shared__ u16 T[64 * 72];
    int blk = blockIdx.x;
    if (blk < 4096) {
        int i = blk * 256 + threadIdx.x;
        float4 v = ((const float4*)x)[i];
        u16x4 o = { f2bf(v.x), f2bf(v.y), f2bf(v.z), f2bf(v.w) };
        ((u16x4*)x_bf)[i] = o;
        return;
    }
    blk -= 4096;
    if (blk < 1024) {   // wq/wk/wv/wo
        int which = blk >> 8, r = blk & 255;
        const float* Ws = which == 0 ? wq : which == 1 ? wk : which == 2 ? wv : wo;
        u16* Wd   = which == 3 ? woT : wqkvT;
        int off   = which == 3 ? 0 : which * 1024;
        float sc  = which == 0 ? qscale : 1.0f;
        transpose_tile(Ws, Wd, 1024, 1024, off, sc, r & 15, r >> 4, T);
        return;
    }
    blk -= 1024;
    if (blk < 1024) {
        transpose_tile(wff1, wff1T, 4096, 1024, 0, 1.0f, blk & 63, blk >> 6, T);
        return;
    }
    blk -= 1024;
    if (blk < 1024) {
        transpose_tile(wff2, wff2T, 1024, 4096, 0, 1.0f, blk & 15, blk >> 4, T);
        return;
    }
    blk -= 1024;
    int i = blk * 256 + threadIdx.x;
    qkv_bias[i] = (i < 1024) ? bq[i] * qscale
                : (i < 2048) ? bk[i - 1024] : bv[i - 2048];
}

// ---------------------------------------------------------------------------
// 128x128 bf16 MFMA GEMM (m97-class): kept for wo (N=1024, K=1024) where a
// 256^2 grid would underfill.  EPI: 3 = bf16 partials at Cout + z*M*N.
// ---------------------------------------------------------------------------
template<int EPI>
__global__ __launch_bounds__(256)
void gemm_bf16(const u16* __restrict__ A, const u16* __restrict__ BT,
               const float* __restrict__ bias, void* __restrict__ Cout,
               u16* __restrict__ Vt, int M, int N, int k_len, int kstride)
{
    __shared__ u16 As[128 * 64];
    __shared__ u16 Bs[128 * 64];
    const int tid  = threadIdx.x;
    const int w    = tid >> 6;
    const int lane = tid & 63;
    const int lm   = lane & 15;
    const int lq   = lane >> 4;
    const int nf = gridDim.x * gridDim.y;
    int f = blockIdx.y * gridDim.x + blockIdx.x;
    f = (f & 7) * (nf >> 3) + (f >> 3);
    const int row0 = (f / gridDim.x) * 128;
    const int col0 = (f % gridDim.x) * 128;
    const int k_off = blockIdx.z * k_len;
    const int wrow = (w >> 1) * 64;
    const int wcol = (w & 1) * 64;

    f32x4 acc[4][4] = {};

    const int r_i = lane >> 3;                 // 0..7 row in 8-group
    const int csw = ((lane & 7) ^ r_i) * 8;    // swizzled src chunk offset
    const u16* a_src = A  + (size_t)(row0 + w * 32 + r_i) * kstride + k_off + csw;
    const u16* b_src = BT + (size_t)(col0 + w * 32 + r_i) * kstride + k_off + csw;
    u16* a_dst = &As[(w * 32) * 64];
    u16* b_dst = &Bs[(w * 32) * 64];

    const int fr0 = (lq ^ (lm & 7)) * 8;
    const int fr1 = ((4 + lq) ^ (lm & 7)) * 8;
    const u16* a_rd = &As[(wrow + lm) * 64];
    const u16* b_rd = &Bs[(wcol + lm) * 64];

    for (int k0 = 0; k0 < k_len; k0 += 64) {
        #pragma unroll
        for (int i = 0; i < 4; ++i) {
            gload_lds16(a_src + k0 + (size_t)(i * 8) * kstride, a_dst + (i * 8) * 64);
            gload_lds16(b_src + k0 + (size_t)(i * 8) * kstride, b_dst + (i * 8) * 64);
        }
        __syncthreads();
        #pragma unroll
        for (int h = 0; h < 2; ++h) {
            const int fo = h ? fr1 : fr0;
            bf16x8 av[4], bv[4];
            #pragma unroll
            for (int m = 0; m < 4; ++m) av[m] = *(const bf16x8*)(a_rd + m * 16 * 64 + fo);
            #pragma unroll
            for (int n = 0; n < 4; ++n) bv[n] = *(const bf16x8*)(b_rd + n * 16 * 64 + fo);
            #pragma unroll
            for (int m = 0; m < 4; ++m)
                #pragma unroll
                for (int n = 0; n < 4; ++n)
                    acc[m][n] = MF(av[m], bv[n], acc[m][n]);
        }
        __syncthreads();
    }

    float bz[4] = {0.f, 0.f, 0.f, 0.f};
    if (EPI != 3) {
        #pragma unroll
        for (int n = 0; n < 4; ++n) bz[n] = bias[col0 + wcol + n * 16 + lm];
    }

    u16* Cz = (u16*)Cout + (EPI == 3 ? (size_t)blockIdx.z * M * N : 0);
    #pragma unroll
    for (int m = 0; m < 4; ++m) {
        #pragma unroll
        for (int e = 0; e < 4; ++e) {
            int row = row0 + wrow + m * 16 + lq * 4 + e;
            #pragma unroll
            for (int n = 0; n < 4; ++n) {
                int col = col0 + wcol + n * 16 + lm;
                float v = acc[m][n][e] + bz[n];
                if (EPI == 1) v = v > 0.f ? v : NEG_SLOPE * v;
                Cz[(size_t)row * N + col] = f2bf(v);
            }
        }
    }
}

// ---------------------------------------------------------------------------
// 256x256 bf16 MFMA GEMM, 8 waves (2M x 4N), BK=64, double-buffered 128KB
// LDS.  Round-7: m201-style per-phase micro-structure — each of the 4
// phases per K-tile is {stage ∥ ds_read frags -> s_barrier ->
// lgkmcnt(0) -> setprio(1) + 16 MFMA + setprio(0) -> s_barrier}.  This is
// the fine interleave m196/m218b isolated as the lever (coarse split was
// round-6's ~1.07x; fine structure + setprio measured +20-40%).
// Counted vmcnt unchanged from round 6 (proof):
//   issue order/iter: B(t+1)x4 @p0, A02(t+1)x2 @p1, A13(t+1)x2 @p2.
//   W1 vmcnt(6) @p0: newest 6 = B(t+1)x4+A13(t)x2 -> B(t),A02(t) landed
//     (phases 0-1 read exactly those).
//   W2 vmcnt(8) @p2: newest 8 = all t+1 loads -> A13(t) landed
//     (phases 2-3 read those).  Tail peel: vmcnt(2)/vmcnt(0).
// Split-K: k_off = z*k_len; EPI 3 partials: z<2 -> Cout + z*M*N,
// z>=2 -> Vt + (z-2)*M*N (two 16MiB partial regions).
// EPI: 1 = bias+LeakyReLU; 3 = partials; 4 = QKV special (V -> Vt^T).
// ---------------------------------------------------------------------------
#define MPHASE(p) \
    __builtin_amdgcn_s_setprio(1); \
    _Pragma("unroll") \
    for (int n = 0; n < 4; ++n) { \
        acc[2*(p)][n]   = MF(a00, bvf[n][0], acc[2*(p)][n]); \
        acc[2*(p)][n]   = MF(a01, bvf[n][1], acc[2*(p)][n]); \
        acc[2*(p)+1][n] = MF(a10, bvf[n][0], acc[2*(p)+1][n]); \
        acc[2*(p)+1][n] = MF(a11, bvf[n][1], acc[2*(p)+1][n]); \
    } \
    __builtin_amdgcn_s_setprio(0);

template<int EPI>
__global__ __launch_bounds__(512, 2)
void gemm256(const u16* __restrict__ A, const u16* __restrict__ BT,
             const float* __restrict__ bias, void* __restrict__ Cout,
             u16* __restrict__ Vt, int M, int N, int k_len, int kstride)
{
    __shared__ u16 AS[2][256 * 64];
    __shared__ u16 BS[2][256 * 64];
    const int tid  = threadIdx.x;
    const int w    = tid >> 6;        // 0..7
    const int lane = tid & 63;
    const int lm   = lane & 15;
    const int lq   = lane >> 4;
    const int wm   = w >> 2;          // 0..1  (M half)
    const int wn   = w & 3;           // 0..3  (N quarter)

    const int gx = gridDim.x;
    const int nf = gx * gridDim.y;
    int f = blockIdx.y * gx + blockIdx.x;
    f = (f & 7) * (nf >> 3) + (f >> 3);          // XCD-contiguous remap
    const int row0 = (f / gx) * 256;
    const int col0 = (f % gx) * 256;
    const int k_off = blockIdx.z * k_len;

    const int r_i = lane >> 3;                   // row within 8-group
    const int csw = ((lane & 7) ^ r_i) * 8;      // pre-swizzled src chunk
    const u16* a_src = A  + (size_t)(row0 + w * 8 + r_i) * kstride + k_off + csw;
    const u16* b_src = BT + (size_t)(col0 + w * 8 + r_i) * kstride + k_off + csw;

    const int fr0 = (lq ^ (lm & 7)) * 8;
    const int fr1 = ((4 + lq) ^ (lm & 7)) * 8;

    f32x4 acc[8][4] = {};
    const int NT = k_len >> 6;

    // prologue: tile 0 -> buffer 0 (all 8 slots), full drain via syncthreads
    #pragma unroll
    for (int j = 0; j < 4; ++j) {
        gload_lds16(a_src + (size_t)(j * 64) * kstride, &AS[0][(j * 64 + w * 8) * 64]);
        gload_lds16(b_src + (size_t)(j * 64) * kstride, &BS[0][(j * 64 + w * 8) * 64]);
    }
    __syncthreads();

    for (int kt = 0; kt < NT; ++kt) {
        const int cb = kt & 1, nb = cb ^ 1;
        const bool pre = (kt + 1) < NT;
        const u16* ar = &AS[cb][0];
        const u16* br = &BS[cb][0];
        u16* aw = &AS[nb][0];
        u16* bw = &BS[nb][0];
        const size_t knext = (size_t)(kt + 1) * 64;

        // ---- phase 0: stage B(t+1); vmcnt; B frags + A rows 0..31 ----
        if (pre) {
            #pragma unroll
            for (int j = 0; j < 4; ++j)
                gload_lds16(b_src + (size_t)(j * 64) * kstride + knext,
                            bw + (j * 64 + w * 8) * 64);
            asm volatile("s_waitcnt vmcnt(6)" ::: "memory");
        } else {
            asm volatile("s_waitcnt vmcnt(2)" ::: "memory");
        }
        bf16x8 bvf[4][2];
        #pragma unroll
        for (int n = 0; n < 4; ++n) {
            bvf[n][0] = *(const bf16x8*)&br[(wn * 64 + n * 16 + lm) * 64 + fr0];
            bvf[n][1] = *(const bf16x8*)&br[(wn * 64 + n * 16 + lm) * 64 + fr1];
        }
        bf16x8 a00 = *(const bf16x8*)&ar[(wm * 128 + lm) * 64 + fr0];
        bf16x8 a01 = *(const bf16x8*)&ar[(wm * 128 + lm) * 64 + fr1];
        bf16x8 a10 = *(const bf16x8*)&ar[(wm * 128 + 16 + lm) * 64 + fr0];
        bf16x8 a11 = *(const bf16x8*)&ar[(wm * 128 + 16 + lm) * 64 + fr1];
        asm volatile("s_waitcnt lgkmcnt(8)" ::: "memory");   // 12 reads issued
        __builtin_amdgcn_s_barrier();
        asm volatile("s_waitcnt lgkmcnt(0)" ::: "memory");
        MPHASE(0)
        __builtin_amdgcn_s_barrier();

        // ---- phase 1: stage A(t+1) slots 0,2; A rows 32..63 ----
        if (pre) {
            gload_lds16(a_src + knext,                         aw + (w * 8) * 64);
            gload_lds16(a_src + (size_t)128 * kstride + knext, aw + (128 + w * 8) * 64);
        }
        a00 = *(const bf16x8*)&ar[(wm * 128 + 32 + lm) * 64 + fr0];
        a01 = *(const bf16x8*)&ar[(wm * 128 + 32 + lm) * 64 + fr1];
        a10 = *(const bf16x8*)&ar[(wm * 128 + 48 + lm) * 64 + fr0];
        a11 = *(const bf16x8*)&ar[(wm * 128 + 48 + lm) * 64 + fr1];
        __builtin_amdgcn_s_barrier();
        asm volatile("s_waitcnt lgkmcnt(0)" ::: "memory");
        MPHASE(1)
        __builtin_amdgcn_s_barrier();

        // ---- phase 2: stage A(t+1) slots 1,3; vmcnt; A rows 64..95 ----
        if (pre) {
            gload_lds16(a_src + (size_t)64 * kstride + knext,  aw + (64 + w * 8) * 64);
            gload_lds16(a_src + (size_t)192 * kstride + knext, aw + (192 + w * 8) * 64);
            asm volatile("s_waitcnt vmcnt(8)" ::: "memory");
        } else {
            asm volatile("s_waitcnt vmcnt(0)" ::: "memory");
        }
        a00 = *(const bf16x8*)&ar[(wm * 128 + 64 + lm) * 64 + fr0];
        a01 = *(const bf16x8*)&ar[(wm * 128 + 64 + lm) * 64 + fr1];
        a10 = *(const bf16x8*)&ar[(wm * 128 + 80 + lm) * 64 + fr0];
        a11 = *(const bf16x8*)&ar[(wm * 128 + 80 + lm) * 64 + fr1];
        __builtin_amdgcn_s_barrier();
        asm volatile("s_waitcnt lgkmcnt(0)" ::: "memory");
        MPHASE(2)
        __builtin_amdgcn_s_barrier();

        // ---- phase 3: A rows 96..127 ----
        a00 = *(const bf16x8*)&ar[(wm * 128 + 96 + lm) * 64 + fr0];
        a01 = *(const bf16x8*)&ar[(wm * 128 + 96 + lm) * 64 + fr1];
        a10 = *(const bf16x8*)&ar[(wm * 128 + 112 + lm) * 64 + fr0];
        a11 = *(const bf16x8*)&ar[(wm * 128 + 112 + lm) * 64 + fr1];
        __builtin_amdgcn_s_barrier();
        asm volatile("s_waitcnt lgkmcnt(0)" ::: "memory");
        MPHASE(3)
        __builtin_amdgcn_s_barrier();
    }

    float bz[4] = {0.f, 0.f, 0.f, 0.f};
    if (EPI != 3) {
        #pragma unroll
        for (int n = 0; n < 4; ++n) bz[n] = bias[col0 + wn * 64 + n * 16 + lm];
    }

    if (EPI == 4 && col0 >= 2048) {
        // V part -> Vt[(b*16+h)*64 + d][2048]
        #pragma unroll
        for (int m = 0; m < 8; ++m) {
            int rbase = row0 + wm * 128 + m * 16 + lq * 4;
            int b = rbase >> 11, s = rbase & 2047;
            #pragma unroll
            for (int n = 0; n < 4; ++n) {
                int c = col0 + wn * 64 + n * 16 + lm - 2048;
                u16x4 pk = { f2bf(acc[m][n][0] + bz[n]), f2bf(acc[m][n][1] + bz[n]),
                             f2bf(acc[m][n][2] + bz[n]), f2bf(acc[m][n][3] + bz[n]) };
                *(u16x4*)&Vt[(size_t)((b * 16 + (c >> 6)) * 64 + (c & 63)) * 2048 + s] = pk;
            }
        }
        return;
    }

    u16* Cz;
    if (EPI == 3) {
        const size_t ps = (size_t)M * N;
        Cz = (blockIdx.z < 2) ? (u16*)Cout + blockIdx.z * ps
                              : Vt + (blockIdx.z - 2) * ps;
    } else {
        Cz = (u16*)Cout;
    }
    #pragma unroll
    for (int m = 0; m < 8; ++m) {
        #pragma unroll
        for (int e = 0; e < 4; ++e) {
            int row = row0 + wm * 128 + m * 16 + lq * 4 + e;
            #pragma unroll
            for (int n = 0; n < 4; ++n) {
                int col = col0 + wn * 64 + n * 16 + lm;
                float v = acc[m][n][e] + bz[n];
                if (EPI == 1) v = v > 0.f ? v : NEG_SLOPE * v;
                Cz[(size_t)row * N + col] = f2bf(v);
            }
        }
    }
}

// ---------------------------------------------------------------------------
// Flash attention, bf16 MFMA. 64 q-rows per block, 4 waves, grid 1024
// (4 blocks/CU, LDS 40960B exactly fills 160KB). 2x2 (q-half x key-half)
// wave split; XCD swizzle (T1, FETCH 69.7->12.3MB verified); wave-private
// swizzled P; cross-wave key-half reduction at end; gload_lds dbuf K/V.
// ---------------------------------------------------------------------------
__global__ __launch_bounds__(256, 4)
void attn_mfma(const u16* __restrict__ QKV, const u16* __restrict__ Vt,
               u16* __restrict__ ctx)
{
    __shared__ u16 QP[64 * 64];       // Q staged (swizzled); later P (swizzled)
    __shared__ u16 Kb[2][64 * 64];
    __shared__ u16 Vb[2][64 * 64];
    const int tid = threadIdx.x, w = tid >> 6, lane = tid & 63;
    const int lm = lane & 15, lq = lane >> 4;
    const int qh = w >> 1;            // q-half: rows qh*32..+31
    const int kh = w & 1;             // key-half: cols kh*32..+31
    int f = blockIdx.y * 32 + blockIdx.x;      // bh-major flat id (1024)
    f = (f & 7) * 128 + (f >> 3);              // XCD-contiguous remap
    const int q0 = (f & 31) * 64;
    const int bh = f >> 5;
    const int b  = bh >> 4, h = bh & 15;
    const size_t row_b = (size_t)b * SS;
    const int ccol = h * DKH;

    const int r_i = lane >> 3;                 // 0..7
    const int csw = ((lane & 7) ^ r_i) * 8;    // swizzled chunk offset
    const u16* ksrc = QKV + (row_b + w * 16 + r_i) * 3072 + 1024 + ccol + csw;
    const u16* vsrc = Vt + ((size_t)bh * 64 + w * 16 + r_i) * SS + csw;
    const u16* qsrc = QKV + (row_b + q0 + w * 16 + r_i) * 3072 + ccol + csw;

    gload_lds16(qsrc,                    &QP[(w * 16) * 64]);
    gload_lds16(qsrc + (size_t)8 * 3072, &QP[(w * 16 + 8) * 64]);
    #pragma unroll
    for (int i = 0; i < 2; ++i) {
        gload_lds16(ksrc + (size_t)(i * 8) * 3072, &Kb[0][(w * 16 + i * 8) * 64]);
        gload_lds16(vsrc + (size_t)(i * 8) * SS,   &Vb[0][(w * 16 + i * 8) * 64]);
    }
    __syncthreads();   // drain DMA: Q/K0/V0 visible

    const int fr0 = (lq ^ (lm & 7)) * 8;
    const int fr1 = ((4 + lq) ^ (lm & 7)) * 8;
    const int frp = kh ? fr1 : fr0;   // P/V inner-k fragment offset (own half)

    bf16x8 aq[2][2];
    #pragma unroll
    for (int m = 0; m < 2; ++m) {
        aq[m][0] = *(const bf16x8*)&QP[(qh * 32 + m * 16 + lm) * 64 + fr0];
        aq[m][1] = *(const bf16x8*)&QP[(qh * 32 + m * 16 + lm) * 64 + fr1];
    }
    __syncthreads();   // all waves hold Q in regs before P overwrites QP

    bf16x8 ones;
    #pragma unroll
    for (int j = 0; j < 8; ++j) ones[j] = (__bf16)1.0f;

    f32x4 o[2][4] = {};    // o[m][n]: q row qh*32+m*16+lq*4+e, d col n*16+lm
    f32x4 lacc[2] = {};    // partial row sums (own key-half)

    for (int kt = 0; kt < SS / 64; ++kt) {
        const int cur = kt & 1;
        if (kt < SS / 64 - 1) {
            const int nxt = cur ^ 1;
            const size_t koff = (size_t)(kt + 1) * 64;
            #pragma unroll
            for (int i = 0; i < 2; ++i) {
                gload_lds16(ksrc + (koff + i * 8) * 3072, &Kb[nxt][(w * 16 + i * 8) * 64]);
                gload_lds16(vsrc + koff + (size_t)(i * 8) * SS, &Vb[nxt][(w * 16 + i * 8) * 64]);
            }
        }
        f32x4 s[2][2] = {};
        #pragma unroll
        for (int n = 0; n < 2; ++n) {
            bf16x8 bk0 = *(const bf16x8*)&Kb[cur][(kh * 32 + n * 16 + lm) * 64 + fr0];
            bf16x8 bk1 = *(const bf16x8*)&Kb[cur][(kh * 32 + n * 16 + lm) * 64 + fr1];
            #pragma unroll
            for (int m = 0; m < 2; ++m) {
                s[m][n] = MF(aq[m][0], bk0, s[m][n]);
                s[m][n] = MF(aq[m][1], bk1, s[m][n]);
            }
        }
        const int rb = lq * 4;
        const int cw = lm & 7;
        #pragma unroll
        for (int m = 0; m < 2; ++m) {
            #pragma unroll
            for (int n = 0; n < 2; ++n) {
                const int cb = kh * 4 + n * 2 + (lm >> 3);
                #pragma unroll
                for (int e = 0; e < 4; ++e) {
                    float p = __builtin_exp2f(s[m][n][e]);
                    const int row = qh * 32 + m * 16 + rb + e;
                    QP[row * 64 + ((cb ^ ((rb + e) & 7)) * 8) + cw] =
                        (u16)((__float_as_uint(p) + 0x8000u) >> 16);
                }
            }
        }
        bf16x8 ap[2];
        #pragma unroll
        for (int m = 0; m < 2; ++m)
            ap[m] = *(const bf16x8*)&QP[(qh * 32 + m * 16 + lm) * 64 + frp];
        #pragma unroll
        for (int n = 0; n < 4; ++n) {
            bf16x8 bv = *(const bf16x8*)&Vb[cur][(n * 16 + lm) * 64 + frp];
            #pragma unroll
            for (int m = 0; m < 2; ++m)
                o[m][n] = MF(ap[m], bv, o[m][n]);
        }
        #pragma unroll
        for (int m = 0; m < 2; ++m)
            lacc[m] = MF(ap[m], ones, lacc[m]);
        __syncthreads();
    }

    if (kh == 1) {
        float* red = (float*)(qh == 0 ? (void*)Kb : (void*)Vb);
        #pragma unroll
        for (int m = 0; m < 2; ++m) {
            #pragma unroll
            for (int n = 0; n < 4; ++n)
                #pragma unroll
                for (int e = 0; e < 4; ++e)
                    red[((m * 4 + n) * 4 + e) * 64 + lane] = o[m][n][e];
            #pragma unroll
            for (int e = 0; e < 4; ++e)
                red[(32 + m * 4 + e) * 64 + lane] = lacc[m][e];
        }
    }
    __syncthreads();
    if (kh == 0) {
        const float* red = (const float*)(qh == 0 ? (void*)Kb : (void*)Vb);
        #pragma unroll
        for (int m = 0; m < 2; ++m) {
            #pragma unroll
            for (int e = 0; e < 4; ++e)
                lacc[m][e] += red[(32 + m * 4 + e) * 64 + lane];
            #pragma unroll
            for (int e = 0; e < 4; ++e) {
                float inv = 1.0f / lacc[m][e];
                int row = q0 + qh * 32 + m * 16 + lq * 4 + e;
                u16* dst = ctx + (row_b + row) * D_MODEL + ccol;
                #pragma unroll
                for (int n = 0; n < 4; ++n) {
                    float v = o[m][n][e] + red[((m * 4 + n) * 4 + e) * 64 + lane];
                    dst[n * 16 + lm] = f2bf(v * inv);
                }
            }
        }
    }
}

// ---------------------------------------------------------------------------
// out = LayerNorm(sum of NPART bf16 partials + cbias + resid) * g + beta.
// NPART=2: partials at C0[row], C1[row].
// NPART=4: partials at C0[row], C0+MTOT*D[row], C1[row], C1+MTOT*D[row];
//          pairwise summation to limit rounding.
// ---------------------------------------------------------------------------
template<int OUTF32, int RESBF, int NPART>
__global__ __launch_bounds__(256)
void add_ln(const u16* __restrict__ C0, const u16* __restrict__ C1,
            const float* __restrict__ cbias, const void* __restrict__ resid,
            const float* __restrict__ g, const float* __restrict__ beta,
            float* __restrict__ outf, u16* __restrict__ outb)
{
    __shared__ float red[8];
    const int row = blockIdx.x;
    const int tid = threadIdx.x;
    float4 pv;
    if (NPART == 2) {
        u16x4 p0 = ((const u16x4*)(C0 + (size_t)row * D_MODEL))[tid];
        u16x4 p1 = ((const u16x4*)(C1 + (size_t)row * D_MODEL))[tid];
        pv = { bf2f(p0.x) + bf2f(p1.x), bf2f(p0.y) + bf2f(p1.y),
               bf2f(p0.z) + bf2f(p1.z), bf2f(p0.w) + bf2f(p1.w) };
    } else {
        const size_t ps = (size_t)MTOT * D_MODEL;
        u16x4 p0 = ((const u16x4*)(C0 + (size_t)row * D_MODEL))[tid];
        u16x4 p1 = ((const u16x4*)(C0 + ps + (size_t)row * D_MODEL))[tid];
        u16x4 p2 = ((const u16x4*)(C1 + (size_t)row * D_MODEL))[tid];
        u16x4 p3 = ((const u16x4*)(C1 + ps + (size_t)row * D_MODEL))[tid];
        pv.x = (bf2f(p0.x) + bf2f(p1.x)) + (bf2f(p2.x) + bf2f(p3.x));
        pv.y = (bf2f(p0.y) + bf2f(p1.y)) + (bf2f(p2.y) + bf2f(p3.y));
        pv.z = (bf2f(p0.z) + bf2f(p1.z)) + (bf2f(p2.z) + bf2f(p3.z));
        pv.w = (bf2f(p0.w) + bf2f(p1.w)) + (bf2f(p2.w) + bf2f(p3.w));
    }
    float4 cb = ((const float4*)cbias)[tid];
    float4 rr;
    if (RESBF) {
        u16x4 rb = ((const u16x4*)((const u16*)resid + (size_t)row * D_MODEL))[tid];
        rr = { bf2f(rb.x), bf2f(rb.y), bf2f(rb.z), bf2f(rb.w) };
    } else {
        rr = ((const float4*)((const float*)resid + (size_t)row * D_MODEL))[tid];
    }
    float4 v = { pv.x + cb.x + rr.x, pv.y + cb.y + rr.y,
                 pv.z + cb.z + rr.z, pv.w + cb.w + rr.w };
    float s  = v.x + v.y + v.z + v.w;
    float sq = v.x*v.x + v.y*v.y + v.z*v.z + v.w*v.w;
    #pragma unroll
    for (int off = 32; off > 0; off >>= 1) {
        s  += __shfl_down(s,  off, 64);
        sq += __shfl_down(sq, off, 64);
    }
    const int wv = tid >> 6;
    if ((tid & 63) == 0) { red[wv] = s; red[4 + wv] = sq; }
    __syncthreads();
    float st  = red[0] + red[1] + red[2] + red[3];
    float sqt = red[4] + red[5] + red[6] + red[7];
    float mu   = st * (1.0f / D_MODEL);
    float var  = sqt * (1.0f / D_MODEL) - mu * mu;
    float rstd = rsqrtf(var + EPSLN);
    float4 gv = ((const float4*)g)[tid];
    float4 bt = ((const float4*)beta)[tid];
    float4 ov;
    ov.x = (v.x - mu) * rstd * gv.x + bt.x;
    ov.y = (v.y - mu) * rstd * gv.y + bt.y;
    ov.z = (v.z - mu) * rstd * gv.z + bt.z;
    ov.w = (v.w - mu) * rstd * gv.w + bt.w;
    if (OUTF32) {
        ((float4*)(outf + (size_t)row * D_MODEL))[tid] = ov;
    } else {
        u16x4 ob = { f2bf(ov.x), f2bf(ov.y), f2bf(ov.z), f2bf(ov.w) };
        ((u16x4*)(outb + (size_t)row * D_MODEL))[tid] = ob;
    }
}

// ---------------------------------------------------------------------------
extern "C" void kernel_launch(void* const* d_in, const int* in_sizes, int n_in,
                              void* d_out, int out_size, void* d_ws, size_t ws_size,
                              hipStream_t stream) {
    const float* x     = (const float*)d_in[0];
    const float* wq    = (const float*)d_in[1];
    const float* bq    = (const float*)d_in[2];
    const float* wk    = (const float*)d_in[3];
    const float* bk    = (const float*)d_in[4];
    const float* wv    = (const float*)d_in[5];
    const float* bv    = (const float*)d_in[6];
    const float* wo    = (const float*)d_in[7];
    const float* bo    = (const float*)d_in[8];
    const float* g1    = (const float*)d_in[9];
    const float* b1    = (const float*)d_in[10];
    const float* w_ff1 = (const float*)d_in[11];
    const float* b_ff1 = (const float*)d_in[12];
    const float* w_ff2 = (const float*)d_in[13];
    const float* b_ff2 = (const float*)d_in[14];
    const float* g2    = (const float*)d_in[15];
    const float* b2    = (const float*)d_in[16];
    float* out = (float*)d_out;

    const float qscale = 0.18033688011112042f;   // log2(e) / sqrt(DK)

    char* W = (char*)d_ws;
    u16*   x_bf    = (u16*)(W + 0);             // 8 MiB (later: ctx; later: ff2 partials 2,3)
    u16*   wqkvT   = (u16*)(W + 8388608);       // 6 MiB (dead after QKV gemm)
    u16*   woT     = (u16*)(W + 14680064);      // 2 MiB (dead after wo gemm)
    u16*   wff1T   = (u16*)(W + 16777216);      // 8 MiB
    u16*   wff2T   = (u16*)(W + 25165824);      // 8 MiB
    u16*   QKV     = (u16*)(W + 33554432);      // 24 MiB (later: ff1, spills into VtG)
    u16*   VtG     = (u16*)(W + 58720256);      // 8 MiB
    u16*   C0      = (u16*)(W + 67108864);      // 8 MiB (partial 0)
    u16*   C1      = (u16*)(W + 75497472);      // 8 MiB (partial 1)
    u16*   h_bf    = (u16*)(W + 83886080);      // 8 MiB
    float* qkv_bias= (float*)(W + 92274688);    // 12 KB
    u16*   ctx     = x_bf;
    u16*   ff1_bf  = QKV;

    dim3 blk(256);
    dim3 blk5(512);
    prep<<<7180, blk, 0, stream>>>(x, x_bf, wq, wk, wv, wo, w_ff1, w_ff2,
                                   wqkvT, woT, wff1T, wff2T,
                                   bq, bk, bv, qkv_bias, qscale);
    gemm256<4><<<dim3(12, 16, 1), blk5, 0, stream>>>(x_bf, wqkvT, qkv_bias, QKV, VtG, MTOT, 3072, 1024, 1024);
    attn_mfma<<<dim3(32, 32), blk, 0, stream>>>(QKV, VtG, ctx);
    gemm_bf16<3><<<dim3(8, 32, 2), blk, 0, stream>>>(ctx, woT, nullptr, C0, nullptr, MTOT, 1024, 512, 1024);
    add_ln<0, 0, 2><<<MTOT, blk, 0, stream>>>(C0, C1, bo, x, g1, b1, nullptr, h_bf);
    gemm256<1><<<dim3(16, 16, 1), blk5, 0, stream>>>(h_bf, wff1T, b_ff1, ff1_bf, nullptr, MTOT, DFF_, 1024, 1024);
    // ff2: 256^2 split-K z=4 (full machine); partials z0,z1 -> C0/C1 regions,
    // z2,z3 -> x_bf region (dead: ctx consumed by wo gemm).
    gemm256<3><<<dim3(4, 16, 4), blk5, 0, stream>>>(ff1_bf, wff2T, nullptr, C0, x_bf, MTOT, 1024, 1024, 4096);
    add_ln<1, 1, 4><<<MTOT, blk, 0, stream>>>(C0, x_bf, b_ff2, h_bf, g2, b2, out, nullptr);
}

// Round 8
// 347.662 us; speedup vs baseline: 1.0981x; 1.0981x over previous
//
#include <hip/hip_runtime.h>
#include <math.h>

#define D_MODEL 1024
#define NHEAD   16
#define DKH     64
#define DFF_    4096
#define BB      2
#define SS      2048
#define MTOT    (BB*SS)
#define EPSLN   1e-6f
#define NEG_SLOPE 0.01f

typedef unsigned short u16;
typedef unsigned int   u32;
typedef __bf16 bf16x8 __attribute__((ext_vector_type(8)));
typedef float  f32x4  __attribute__((ext_vector_type(4)));
typedef u16    u16x4  __attribute__((ext_vector_type(4)));

__device__ __forceinline__ u16 f2bf(float f) {
    u32 u = __float_as_uint(f);
    u = (u + 0x7fffu + ((u >> 16) & 1u)) >> 16;
    return (u16)u;
}
__device__ __forceinline__ float bf2f(u16 u) {
    return __uint_as_float(((u32)u) << 16);
}

__device__ __forceinline__ void gload_lds16(const u16* g, u16* l) {
    __builtin_amdgcn_global_load_lds(
        (const __attribute__((address_space(1))) u32*)g,
        (__attribute__((address_space(3))) u32*)l,
        16, 0, 0);
}

#define MF(a, b, c) __builtin_amdgcn_mfma_f32_16x16x32_bf16(a, b, c, 0, 0, 0)

// ---------------------------------------------------------------------------
// 64x64 fp32->bf16 transpose tile (device helper for prep kernel)
// ---------------------------------------------------------------------------
__device__ __forceinline__ void transpose_tile(const float* __restrict__ W,
        u16* __restrict__ WT, int N, int out_stride, int out_row_off,
        float scale, int bx, int by, u16* T)
{
    const int t  = threadIdx.x;
    const int n0 = bx * 64;
    const int k0 = by * 64;
    #pragma unroll
    for (int i = 0; i < 4; ++i) {
        int r = i * 16 + (t >> 4);          // k
        int c = (t & 15) * 4;               // n
        float4 v = *(const float4*)&W[(size_t)(k0 + r) * N + n0 + c];
        T[(c + 0) * 72 + r] = f2bf(v.x * scale);
        T[(c + 1) * 72 + r] = f2bf(v.y * scale);
        T[(c + 2) * 72 + r] = f2bf(v.z * scale);
        T[(c + 3) * 72 + r] = f2bf(v.w * scale);
    }
    __syncthreads();
    #pragma unroll
    for (int i = 0; i < 4; ++i) {
        int nr = i * 16 + (t >> 4);
        int kc = (t & 15) * 4;
        u16x4 o = { T[nr*72 + kc], T[nr*72 + kc + 1], T[nr*72 + kc + 2], T[nr*72 + kc + 3] };
        *(u16x4*)&WT[(size_t)(out_row_off + n0 + nr) * out_stride + k0 + kc] = o;
    }
}

// ---------------------------------------------------------------------------
// Fused prep: x f32->bf16 | 4 square W transposes | ff1 | ff2 | bias concat.
// ---------------------------------------------------------------------------
__global__ __launch_bounds__(256)
void prep(const float* __restrict__ x, u16* __restrict__ x_bf,
          const float* __restrict__ wq, const float* __restrict__ wk,
          const float* __restrict__ wv, const float* __restrict__ wo,
          const float* __restrict__ wff1, const float* __restrict__ wff2,
          u16* __restrict__ wqkvT, u16* __restrict__ woT,
          u16* __restrict__ wff1T, u16* __restrict__ wff2T,
          const float* __restrict__ bq, const float* __restrict__ bk,
          const float* __restrict__ bv, float* __restrict__ qkv_bias,
          float qscale)
{
    __shared__ u16 T[64 * 72];
    int blk = blockIdx.x;
    if (blk < 4096) {
        int i = blk * 256 + threadIdx.x;
        float4 v = ((const float4*)x)[i];
        u16x4 o = { f2bf(v.x), f2bf(v.y), f2bf(v.z), f2bf(v.w) };
        ((u16x4*)x_bf)[i] = o;
        return;
    }
    blk -= 4096;
    if (blk < 1024) {   // wq/wk/wv/wo
        int which = blk >> 8, r = blk & 255;
        const float* Ws = which == 0 ? wq : which == 1 ? wk : which == 2 ? wv : wo;
        u16* Wd   = which == 3 ? woT : wqkvT;
        int off   = which == 3 ? 0 : which * 1024;
        float sc  = which == 0 ? qscale : 1.0f;
        transpose_tile(Ws, Wd, 1024, 1024, off, sc, r & 15, r >> 4, T);
        return;
    }
    blk -= 1024;
    if (blk < 1024) {
        transpose_tile(wff1, wff1T, 4096, 1024, 0, 1.0f, blk & 63, blk >> 6, T);
        return;
    }
    blk -= 1024;
    if (blk < 1024) {
        transpose_tile(wff2, wff2T, 1024, 4096, 0, 1.0f, blk & 15, blk >> 4, T);
        return;
    }
    blk -= 1024;
    int i = blk * 256 + threadIdx.x;
    qkv_bias[i] = (i < 1024) ? bq[i] * qscale
                : (i < 2048) ? bk[i - 1024] : bv[i - 2048];
}

// ---------------------------------------------------------------------------
// 128x128 bf16 MFMA GEMM (m97-class): kept for wo (N=1024, K=1024 split z=2)
// where a 256^2 grid would underfill.  EPI: 3 = bf16 partials at Cout+z*M*N.
// ---------------------------------------------------------------------------
template<int EPI>
__global__ __launch_bounds__(256)
void gemm_bf16(const u16* __restrict__ A, const u16* __restrict__ BT,
               const float* __restrict__ bias, void* __restrict__ Cout,
               u16* __restrict__ Vt, int M, int N, int k_len, int kstride)
{
    __shared__ u16 As[128 * 64];
    __shared__ u16 Bs[128 * 64];
    const int tid  = threadIdx.x;
    const int w    = tid >> 6;
    const int lane = tid & 63;
    const int lm   = lane & 15;
    const int lq   = lane >> 4;
    const int nf = gridDim.x * gridDim.y;
    int f = blockIdx.y * gridDim.x + blockIdx.x;
    f = (f & 7) * (nf >> 3) + (f >> 3);
    const int row0 = (f / gridDim.x) * 128;
    const int col0 = (f % gridDim.x) * 128;
    const int k_off = blockIdx.z * k_len;
    const int wrow = (w >> 1) * 64;
    const int wcol = (w & 1) * 64;

    f32x4 acc[4][4] = {};

    const int r_i = lane >> 3;                 // 0..7 row in 8-group
    const int csw = ((lane & 7) ^ r_i) * 8;    // swizzled src chunk offset
    const u16* a_src = A  + (size_t)(row0 + w * 32 + r_i) * kstride + k_off + csw;
    const u16* b_src = BT + (size_t)(col0 + w * 32 + r_i) * kstride + k_off + csw;
    u16* a_dst = &As[(w * 32) * 64];
    u16* b_dst = &Bs[(w * 32) * 64];

    const int fr0 = (lq ^ (lm & 7)) * 8;
    const int fr1 = ((4 + lq) ^ (lm & 7)) * 8;
    const u16* a_rd = &As[(wrow + lm) * 64];
    const u16* b_rd = &Bs[(wcol + lm) * 64];

    for (int k0 = 0; k0 < k_len; k0 += 64) {
        #pragma unroll
        for (int i = 0; i < 4; ++i) {
            gload_lds16(a_src + k0 + (size_t)(i * 8) * kstride, a_dst + (i * 8) * 64);
            gload_lds16(b_src + k0 + (size_t)(i * 8) * kstride, b_dst + (i * 8) * 64);
        }
        __syncthreads();
        #pragma unroll
        for (int h = 0; h < 2; ++h) {
            const int fo = h ? fr1 : fr0;
            bf16x8 av[4], bv[4];
            #pragma unroll
            for (int m = 0; m < 4; ++m) av[m] = *(const bf16x8*)(a_rd + m * 16 * 64 + fo);
            #pragma unroll
            for (int n = 0; n < 4; ++n) bv[n] = *(const bf16x8*)(b_rd + n * 16 * 64 + fo);
            #pragma unroll
            for (int m = 0; m < 4; ++m)
                #pragma unroll
                for (int n = 0; n < 4; ++n)
                    acc[m][n] = MF(av[m], bv[n], acc[m][n]);
        }
        __syncthreads();
    }

    float bz[4] = {0.f, 0.f, 0.f, 0.f};
    if (EPI != 3) {
        #pragma unroll
        for (int n = 0; n < 4; ++n) bz[n] = bias[col0 + wcol + n * 16 + lm];
    }

    u16* Cz = (u16*)Cout + (EPI == 3 ? (size_t)blockIdx.z * M * N : 0);
    #pragma unroll
    for (int m = 0; m < 4; ++m) {
        #pragma unroll
        for (int e = 0; e < 4; ++e) {
            int row = row0 + wrow + m * 16 + lq * 4 + e;
            #pragma unroll
            for (int n = 0; n < 4; ++n) {
                int col = col0 + wcol + n * 16 + lm;
                float v = acc[m][n][e] + bz[n];
                if (EPI == 1) v = v > 0.f ? v : NEG_SLOPE * v;
                Cz[(size_t)row * N + col] = f2bf(v);
            }
        }
    }
}

// ---------------------------------------------------------------------------
// 256x256 bf16 MFMA GEMM, 8 waves (2M x 4N), BK=64, double-buffered 128KB
// LDS, ROUND-6 COARSE 4-phase schedule with COUNTED vmcnt (never 0
// mid-loop) — the best-measured structure at this grid scale (round-7's
// 8-barrier-per-tile fine port regressed 31us; reverted).
// Staging (tile t+1, issued during tile t):
//   phase0: B slots 0..3   phase1: A slots 0,2   phase2: A slots 1,3
// Waits (in-order VMEM retirement):
//   before phase0 frags: vmcnt(6)  [newest 6 = B(t+1)x4 + A13(t)x2
//     -> B(t), A02(t) landed; phases 0-1 read exactly those]
//   before phase2 frags: vmcnt(8)  [newest 8 = all t+1 -> A13(t) landed]
//   tail peel: vmcnt(2) / vmcnt(0).
// One s_barrier per K-tile; no drain-to-0 mid-loop.
// Split-K: k_off = z*k_len; EPI 3 partials: z<2 -> Cout + z*M*N,
// z>=2 -> Vt + (z-2)*M*N.
// EPI: 1 = bias+LeakyReLU; 3 = partials; 4 = QKV special (V -> Vt^T).
// ---------------------------------------------------------------------------
#define GPHASE(p) { \
    bf16x8 a0h0 = *(const bf16x8*)&ar[(wm * 128 + (p) * 32 + lm) * 64 + fr0]; \
    bf16x8 a0h1 = *(const bf16x8*)&ar[(wm * 128 + (p) * 32 + lm) * 64 + fr1]; \
    bf16x8 a1h0 = *(const bf16x8*)&ar[(wm * 128 + (p) * 32 + 16 + lm) * 64 + fr0]; \
    bf16x8 a1h1 = *(const bf16x8*)&ar[(wm * 128 + (p) * 32 + 16 + lm) * 64 + fr1]; \
    _Pragma("unroll") \
    for (int n = 0; n < 4; ++n) { \
        acc[2*(p)][n]   = MF(a0h0, bvf[n][0], acc[2*(p)][n]); \
        acc[2*(p)][n]   = MF(a0h1, bvf[n][1], acc[2*(p)][n]); \
        acc[2*(p)+1][n] = MF(a1h0, bvf[n][0], acc[2*(p)+1][n]); \
        acc[2*(p)+1][n] = MF(a1h1, bvf[n][1], acc[2*(p)+1][n]); \
    } }

template<int EPI>
__global__ __launch_bounds__(512, 2)
void gemm256(const u16* __restrict__ A, const u16* __restrict__ BT,
             const float* __restrict__ bias, void* __restrict__ Cout,
             u16* __restrict__ Vt, int M, int N, int k_len, int kstride)
{
    __shared__ u16 AS[2][256 * 64];
    __shared__ u16 BS[2][256 * 64];
    const int tid  = threadIdx.x;
    const int w    = tid >> 6;        // 0..7
    const int lane = tid & 63;
    const int lm   = lane & 15;
    const int lq   = lane >> 4;
    const int wm   = w >> 2;          // 0..1  (M half)
    const int wn   = w & 3;           // 0..3  (N quarter)

    const int gx = gridDim.x;
    const int nf = gx * gridDim.y;
    int f = blockIdx.y * gx + blockIdx.x;
    f = (f & 7) * (nf >> 3) + (f >> 3);          // XCD-contiguous remap
    const int row0 = (f / gx) * 256;
    const int col0 = (f % gx) * 256;
    const int k_off = blockIdx.z * k_len;

    const int r_i = lane >> 3;                   // row within 8-group
    const int csw = ((lane & 7) ^ r_i) * 8;      // pre-swizzled src chunk
    const u16* a_src = A  + (size_t)(row0 + w * 8 + r_i) * kstride + k_off + csw;
    const u16* b_src = BT + (size_t)(col0 + w * 8 + r_i) * kstride + k_off + csw;

    const int fr0 = (lq ^ (lm & 7)) * 8;
    const int fr1 = ((4 + lq) ^ (lm & 7)) * 8;

    f32x4 acc[8][4] = {};
    const int NT = k_len >> 6;

    // prologue: tile 0 -> buffer 0 (all 8 slots), drain, align
    #pragma unroll
    for (int j = 0; j < 4; ++j) {
        gload_lds16(a_src + (size_t)(j * 64) * kstride, &AS[0][(j * 64 + w * 8) * 64]);
        gload_lds16(b_src + (size_t)(j * 64) * kstride, &BS[0][(j * 64 + w * 8) * 64]);
    }
    __syncthreads();

    for (int kt = 0; kt < NT; ++kt) {
        const int cb = kt & 1, nb = cb ^ 1;
        const bool pre = (kt + 1) < NT;
        const u16* ar = &AS[cb][0];
        const u16* br = &BS[cb][0];
        u16* aw = &AS[nb][0];
        u16* bw = &BS[nb][0];
        const size_t knext = (size_t)(kt + 1) * 64;

        // ---- phase 0: issue B(t+1) slots 0..3; counted wait; B frags; MFMA m0,m1
        if (pre) {
            #pragma unroll
            for (int j = 0; j < 4; ++j)
                gload_lds16(b_src + (size_t)(j * 64) * kstride + knext,
                            bw + (j * 64 + w * 8) * 64);
            asm volatile("s_waitcnt vmcnt(6)" ::: "memory");
        } else {
            asm volatile("s_waitcnt vmcnt(2)" ::: "memory");
        }
        bf16x8 bvf[4][2];
        #pragma unroll
        for (int n = 0; n < 4; ++n) {
            bvf[n][0] = *(const bf16x8*)&br[(wn * 64 + n * 16 + lm) * 64 + fr0];
            bvf[n][1] = *(const bf16x8*)&br[(wn * 64 + n * 16 + lm) * 64 + fr1];
        }
        GPHASE(0)
        // ---- phase 1: issue A(t+1) slots 0,2; MFMA m2,m3
        if (pre) {
            gload_lds16(a_src + knext,                                 aw + (w * 8) * 64);
            gload_lds16(a_src + (size_t)128 * kstride + knext,         aw + (128 + w * 8) * 64);
        }
        GPHASE(1)
        // ---- phase 2: issue A(t+1) slots 1,3; counted wait; MFMA m4,m5
        if (pre) {
            gload_lds16(a_src + (size_t)64 * kstride + knext,          aw + (64 + w * 8) * 64);
            gload_lds16(a_src + (size_t)192 * kstride + knext,         aw + (192 + w * 8) * 64);
            asm volatile("s_waitcnt vmcnt(8)" ::: "memory");
        } else {
            asm volatile("s_waitcnt vmcnt(0)" ::: "memory");
        }
        GPHASE(2)
        // ---- phase 3: MFMA m6,m7
        GPHASE(3)
        asm volatile("" ::: "memory");
        __builtin_amdgcn_s_barrier();   // all waves done reading cb; no vm drain
    }

    float bz[4] = {0.f, 0.f, 0.f, 0.f};
    if (EPI != 3) {
        #pragma unroll
        for (int n = 0; n < 4; ++n) bz[n] = bias[col0 + wn * 64 + n * 16 + lm];
    }

    if (EPI == 4 && col0 >= 2048) {
        // V part -> Vt[(b*16+h)*64 + d][2048]
        #pragma unroll
        for (int m = 0; m < 8; ++m) {
            int rbase = row0 + wm * 128 + m * 16 + lq * 4;
            int b = rbase >> 11, s = rbase & 2047;
            #pragma unroll
            for (int n = 0; n < 4; ++n) {
                int c = col0 + wn * 64 + n * 16 + lm - 2048;
                u16x4 pk = { f2bf(acc[m][n][0] + bz[n]), f2bf(acc[m][n][1] + bz[n]),
                             f2bf(acc[m][n][2] + bz[n]), f2bf(acc[m][n][3] + bz[n]) };
                *(u16x4*)&Vt[(size_t)((b * 16 + (c >> 6)) * 64 + (c & 63)) * 2048 + s] = pk;
            }
        }
        return;
    }

    u16* Cz;
    if (EPI == 3) {
        const size_t ps = (size_t)M * N;
        Cz = (blockIdx.z < 2) ? (u16*)Cout + blockIdx.z * ps
                              : Vt + (blockIdx.z - 2) * ps;
    } else {
        Cz = (u16*)Cout;
    }
    #pragma unroll
    for (int m = 0; m < 8; ++m) {
        #pragma unroll
        for (int e = 0; e < 4; ++e) {
            int row = row0 + wm * 128 + m * 16 + lq * 4 + e;
            #pragma unroll
            for (int n = 0; n < 4; ++n) {
                int col = col0 + wn * 64 + n * 16 + lm;
                float v = acc[m][n][e] + bz[n];
                if (EPI == 1) v = v > 0.f ? v : NEG_SLOPE * v;
                Cz[(size_t)row * N + col] = f2bf(v);
            }
        }
    }
}

// ---------------------------------------------------------------------------
// Flash attention, bf16 MFMA. 64 q-rows per block, 4 waves, grid 1024
// (4 blocks/CU, LDS 40960B exactly fills 160KB). 2x2 (q-half x key-half)
// wave split; XCD swizzle (T1, FETCH 69.7->12.3MB verified); wave-private
// swizzled P; cross-wave key-half reduction at end; gload_lds dbuf K/V.
// ---------------------------------------------------------------------------
__global__ __launch_bounds__(256, 4)
void attn_mfma(const u16* __restrict__ QKV, const u16* __restrict__ Vt,
               u16* __restrict__ ctx)
{
    __shared__ u16 QP[64 * 64];       // Q staged (swizzled); later P (swizzled)
    __shared__ u16 Kb[2][64 * 64];
    __shared__ u16 Vb[2][64 * 64];
    const int tid = threadIdx.x, w = tid >> 6, lane = tid & 63;
    const int lm = lane & 15, lq = lane >> 4;
    const int qh = w >> 1;            // q-half: rows qh*32..+31
    const int kh = w & 1;             // key-half: cols kh*32..+31
    int f = blockIdx.y * 32 + blockIdx.x;      // bh-major flat id (1024)
    f = (f & 7) * 128 + (f >> 3);              // XCD-contiguous remap
    const int q0 = (f & 31) * 64;
    const int bh = f >> 5;
    const int b  = bh >> 4, h = bh & 15;
    const size_t row_b = (size_t)b * SS;
    const int ccol = h * DKH;

    const int r_i = lane >> 3;                 // 0..7
    const int csw = ((lane & 7) ^ r_i) * 8;    // swizzled chunk offset
    const u16* ksrc = QKV + (row_b + w * 16 + r_i) * 3072 + 1024 + ccol + csw;
    const u16* vsrc = Vt + ((size_t)bh * 64 + w * 16 + r_i) * SS + csw;
    const u16* qsrc = QKV + (row_b + q0 + w * 16 + r_i) * 3072 + ccol + csw;

    gload_lds16(qsrc,                    &QP[(w * 16) * 64]);
    gload_lds16(qsrc + (size_t)8 * 3072, &QP[(w * 16 + 8) * 64]);
    #pragma unroll
    for (int i = 0; i < 2; ++i) {
        gload_lds16(ksrc + (size_t)(i * 8) * 3072, &Kb[0][(w * 16 + i * 8) * 64]);
        gload_lds16(vsrc + (size_t)(i * 8) * SS,   &Vb[0][(w * 16 + i * 8) * 64]);
    }
    __syncthreads();   // drain DMA: Q/K0/V0 visible

    const int fr0 = (lq ^ (lm & 7)) * 8;
    const int fr1 = ((4 + lq) ^ (lm & 7)) * 8;
    const int frp = kh ? fr1 : fr0;   // P/V inner-k fragment offset (own half)

    bf16x8 aq[2][2];
    #pragma unroll
    for (int m = 0; m < 2; ++m) {
        aq[m][0] = *(const bf16x8*)&QP[(qh * 32 + m * 16 + lm) * 64 + fr0];
        aq[m][1] = *(const bf16x8*)&QP[(qh * 32 + m * 16 + lm) * 64 + fr1];
    }
    __syncthreads();   // all waves hold Q in regs before P overwrites QP

    bf16x8 ones;
    #pragma unroll
    for (int j = 0; j < 8; ++j) ones[j] = (__bf16)1.0f;

    f32x4 o[2][4] = {};    // o[m][n]: q row qh*32+m*16+lq*4+e, d col n*16+lm
    f32x4 lacc[2] = {};    // partial row sums (own key-half)

    for (int kt = 0; kt < SS / 64; ++kt) {
        const int cur = kt & 1;
        if (kt < SS / 64 - 1) {
            const int nxt = cur ^ 1;
            const size_t koff = (size_t)(kt + 1) * 64;
            #pragma unroll
            for (int i = 0; i < 2; ++i) {
                gload_lds16(ksrc + (koff + i * 8) * 3072, &Kb[nxt][(w * 16 + i * 8) * 64]);
                gload_lds16(vsrc + koff + (size_t)(i * 8) * SS, &Vb[nxt][(w * 16 + i * 8) * 64]);
            }
        }
        f32x4 s[2][2] = {};
        #pragma unroll
        for (int n = 0; n < 2; ++n) {
            bf16x8 bk0 = *(const bf16x8*)&Kb[cur][(kh * 32 + n * 16 + lm) * 64 + fr0];
            bf16x8 bk1 = *(const bf16x8*)&Kb[cur][(kh * 32 + n * 16 + lm) * 64 + fr1];
            #pragma unroll
            for (int m = 0; m < 2; ++m) {
                s[m][n] = MF(aq[m][0], bk0, s[m][n]);
                s[m][n] = MF(aq[m][1], bk1, s[m][n]);
            }
        }
        const int rb = lq * 4;
        const int cw = lm & 7;
        #pragma unroll
        for (int m = 0; m < 2; ++m) {
            #pragma unroll
            for (int n = 0; n < 2; ++n) {
                const int cb = kh * 4 + n * 2 + (lm >> 3);
                #pragma unroll
                for (int e = 0; e < 4; ++e) {
                    float p = __builtin_exp2f(s[m][n][e]);
                    const int row = qh * 32 + m * 16 + rb + e;
                    QP[row * 64 + ((cb ^ ((rb + e) & 7)) * 8) + cw] =
                        (u16)((__float_as_uint(p) + 0x8000u) >> 16);
                }
            }
        }
        bf16x8 ap[2];
        #pragma unroll
        for (int m = 0; m < 2; ++m)
            ap[m] = *(const bf16x8*)&QP[(qh * 32 + m * 16 + lm) * 64 + frp];
        #pragma unroll
        for (int n = 0; n < 4; ++n) {
            bf16x8 bv = *(const bf16x8*)&Vb[cur][(n * 16 + lm) * 64 + frp];
            #pragma unroll
            for (int m = 0; m < 2; ++m)
                o[m][n] = MF(ap[m], bv, o[m][n]);
        }
        #pragma unroll
        for (int m = 0; m < 2; ++m)
            lacc[m] = MF(ap[m], ones, lacc[m]);
        __syncthreads();
    }

    if (kh == 1) {
        float* red = (float*)(qh == 0 ? (void*)Kb : (void*)Vb);
        #pragma unroll
        for (int m = 0; m < 2; ++m) {
            #pragma unroll
            for (int n = 0; n < 4; ++n)
                #pragma unroll
                for (int e = 0; e < 4; ++e)
                    red[((m * 4 + n) * 4 + e) * 64 + lane] = o[m][n][e];
            #pragma unroll
            for (int e = 0; e < 4; ++e)
                red[(32 + m * 4 + e) * 64 + lane] = lacc[m][e];
        }
    }
    __syncthreads();
    if (kh == 0) {
        const float* red = (const float*)(qh == 0 ? (void*)Kb : (void*)Vb);
        #pragma unroll
        for (int m = 0; m < 2; ++m) {
            #pragma unroll
            for (int e = 0; e < 4; ++e)
                lacc[m][e] += red[(32 + m * 4 + e) * 64 + lane];
            #pragma unroll
            for (int e = 0; e < 4; ++e) {
                float inv = 1.0f / lacc[m][e];
                int row = q0 + qh * 32 + m * 16 + lq * 4 + e;
                u16* dst = ctx + (row_b + row) * D_MODEL + ccol;
                #pragma unroll
                for (int n = 0; n < 4; ++n) {
                    float v = o[m][n][e] + red[((m * 4 + n) * 4 + e) * 64 + lane];
                    dst[n * 16 + lm] = f2bf(v * inv);
                }
            }
        }
    }
}

// ---------------------------------------------------------------------------
// out = LayerNorm(sum of NPART bf16 partials + cbias + resid) * g + beta.
// NPART=2: partials at C0[row], C1[row].
// NPART=4: partials at C0[row], C0+MTOT*D[row], C1[row], C1+MTOT*D[row];
//          pairwise summation (validated round 7, absmax unchanged).
// ---------------------------------------------------------------------------
template<int OUTF32, int RESBF, int NPART>
__global__ __launch_bounds__(256)
void add_ln(const u16* __restrict__ C0, const u16* __restrict__ C1,
            const float* __restrict__ cbias, const void* __restrict__ resid,
            const float* __restrict__ g, const float* __restrict__ beta,
            float* __restrict__ outf, u16* __restrict__ outb)
{
    __shared__ float red[8];
    const int row = blockIdx.x;
    const int tid = threadIdx.x;
    float4 pv;
    if (NPART == 2) {
        u16x4 p0 = ((const u16x4*)(C0 + (size_t)row * D_MODEL))[tid];
        u16x4 p1 = ((const u16x4*)(C1 + (size_t)row * D_MODEL))[tid];
        pv = { bf2f(p0.x) + bf2f(p1.x), bf2f(p0.y) + bf2f(p1.y),
               bf2f(p0.z) + bf2f(p1.z), bf2f(p0.w) + bf2f(p1.w) };
    } else {
        const size_t ps = (size_t)MTOT * D_MODEL;
        u16x4 p0 = ((const u16x4*)(C0 + (size_t)row * D_MODEL))[tid];
        u16x4 p1 = ((const u16x4*)(C0 + ps + (size_t)row * D_MODEL))[tid];
        u16x4 p2 = ((const u16x4*)(C1 + (size_t)row * D_MODEL))[tid];
        u16x4 p3 = ((const u16x4*)(C1 + ps + (size_t)row * D_MODEL))[tid];
        pv.x = (bf2f(p0.x) + bf2f(p1.x)) + (bf2f(p2.x) + bf2f(p3.x));
        pv.y = (bf2f(p0.y) + bf2f(p1.y)) + (bf2f(p2.y) + bf2f(p3.y));
        pv.z = (bf2f(p0.z) + bf2f(p1.z)) + (bf2f(p2.z) + bf2f(p3.z));
        pv.w = (bf2f(p0.w) + bf2f(p1.w)) + (bf2f(p2.w) + bf2f(p3.w));
    }
    float4 cb = ((const float4*)cbias)[tid];
    float4 rr;
    if (RESBF) {
        u16x4 rb = ((const u16x4*)((const u16*)resid + (size_t)row * D_MODEL))[tid];
        rr = { bf2f(rb.x), bf2f(rb.y), bf2f(rb.z), bf2f(rb.w) };
    } else {
        rr = ((const float4*)((const float*)resid + (size_t)row * D_MODEL))[tid];
    }
    float4 v = { pv.x + cb.x + rr.x, pv.y + cb.y + rr.y,
                 pv.z + cb.z + rr.z, pv.w + cb.w + rr.w };
    float s  = v.x + v.y + v.z + v.w;
    float sq = v.x*v.x + v.y*v.y + v.z*v.z + v.w*v.w;
    #pragma unroll
    for (int off = 32; off > 0; off >>= 1) {
        s  += __shfl_down(s,  off, 64);
        sq += __shfl_down(sq, off, 64);
    }
    const int wv = tid >> 6;
    if ((tid & 63) == 0) { red[wv] = s; red[4 + wv] = sq; }
    __syncthreads();
    float st  = red[0] + red[1] + red[2] + red[3];
    float sqt = red[4] + red[5] + red[6] + red[7];
    float mu   = st * (1.0f / D_MODEL);
    float var  = sqt * (1.0f / D_MODEL) - mu * mu;
    float rstd = rsqrtf(var + EPSLN);
    float4 gv = ((const float4*)g)[tid];
    float4 bt = ((const float4*)beta)[tid];
    float4 ov;
    ov.x = (v.x - mu) * rstd * gv.x + bt.x;
    ov.y = (v.y - mu) * rstd * gv.y + bt.y;
    ov.z = (v.z - mu) * rstd * gv.z + bt.z;
    ov.w = (v.w - mu) * rstd * gv.w + bt.w;
    if (OUTF32) {
        ((float4*)(outf + (size_t)row * D_MODEL))[tid] = ov;
    } else {
        u16x4 ob = { f2bf(ov.x), f2bf(ov.y), f2bf(ov.z), f2bf(ov.w) };
        ((u16x4*)(outb + (size_t)row * D_MODEL))[tid] = ob;
    }
}

// ---------------------------------------------------------------------------
extern "C" void kernel_launch(void* const* d_in, const int* in_sizes, int n_in,
                              void* d_out, int out_size, void* d_ws, size_t ws_size,
                              hipStream_t stream) {
    const float* x     = (const float*)d_in[0];
    const float* wq    = (const float*)d_in[1];
    const float* bq    = (const float*)d_in[2];
    const float* wk    = (const float*)d_in[3];
    const float* bk    = (const float*)d_in[4];
    const float* wv    = (const float*)d_in[5];
    const float* bv    = (const float*)d_in[6];
    const float* wo    = (const float*)d_in[7];
    const float* bo    = (const float*)d_in[8];
    const float* g1    = (const float*)d_in[9];
    const float* b1    = (const float*)d_in[10];
    const float* w_ff1 = (const float*)d_in[11];
    const float* b_ff1 = (const float*)d_in[12];
    const float* w_ff2 = (const float*)d_in[13];
    const float* b_ff2 = (const float*)d_in[14];
    const float* g2    = (const float*)d_in[15];
    const float* b2    = (const float*)d_in[16];
    float* out = (float*)d_out;

    const float qscale = 0.18033688011112042f;   // log2(e) / sqrt(DK)

    char* W = (char*)d_ws;
    u16*   x_bf    = (u16*)(W + 0);             // 8 MiB (later: ctx; later: ff2 partials 2,3)
    u16*   wqkvT   = (u16*)(W + 8388608);       // 6 MiB (dead after QKV gemm; later partial 3)
    u16*   woT     = (u16*)(W + 14680064);      // 2 MiB (dead after wo gemm; later partial 3)
    u16*   wff1T   = (u16*)(W + 16777216);      // 8 MiB
    u16*   wff2T   = (u16*)(W + 25165824);      // 8 MiB
    u16*   QKV     = (u16*)(W + 33554432);      // 24 MiB (later: ff1)
    u16*   VtG     = (u16*)(W + 58720256);      // 8 MiB
    u16*   C0      = (u16*)(W + 67108864);      // 8 MiB (partial 0)
    u16*   C1      = (u16*)(W + 75497472);      // 8 MiB (partial 1)
    u16*   h_bf    = (u16*)(W + 83886080);      // 8 MiB
    float* qkv_bias= (float*)(W + 92274688);    // 12 KB
    u16*   ctx     = x_bf;
    u16*   ff1_bf  = QKV;

    dim3 blk(256);
    dim3 blk5(512);
    prep<<<7180, blk, 0, stream>>>(x, x_bf, wq, wk, wv, wo, w_ff1, w_ff2,
                                   wqkvT, woT, wff1T, wff2T,
                                   bq, bk, bv, qkv_bias, qscale);
    gemm256<4><<<dim3(12, 16, 1), blk5, 0, stream>>>(x_bf, wqkvT, qkv_bias, QKV, VtG, MTOT, 3072, 1024, 1024);
    attn_mfma<<<dim3(32, 32), blk, 0, stream>>>(QKV, VtG, ctx);
    gemm_bf16<3><<<dim3(8, 32, 2), blk, 0, stream>>>(ctx, woT, nullptr, C0, nullptr, MTOT, 1024, 512, 1024);
    add_ln<0, 0, 2><<<MTOT, blk, 0, stream>>>(C0, C1, bo, x, g1, b1, nullptr, h_bf);
    gemm256<1><<<dim3(16, 16, 1), blk5, 0, stream>>>(h_bf, wff1T, b_ff1, ff1_bf, nullptr, MTOT, DFF_, 1024, 1024);
    // ff2: 256^2 coarse split-K z=4 (grid 256 = 1 block/CU); partials
    // z0,z1 -> C0/C1 regions, z2,z3 -> x_bf region (ctx dead after wo gemm).
    gemm256<3><<<dim3(4, 16, 4), blk5, 0, stream>>>(ff1_bf, wff2T, nullptr, C0, x_bf, MTOT, 1024, 1024, 4096);
    add_ln<1, 1, 4><<<MTOT, blk, 0, stream>>>(C0, x_bf, b_ff2, h_bf, g2, b2, out, nullptr);
}